// Round 1
// baseline (3072.079 us; speedup 1.0000x reference)
//
#include <hip/hip_runtime.h>

#define N_NODESC 100000
#define N_EDGESC 600000
#define HDIM 128
#define H3 384
#define NUM_STEPSC 5

#define SCAN_BLOCK 256
#define SCAN_CHUNK 1024

__device__ __forceinline__ float sigmoidf_(float x) { return 1.0f / (1.0f + expf(-x)); }

// W_cT[k][o] = sum_m W_ih[o][m]*W_msg[m][k];  W_hhT[k][o] = W_hh[o][k];  b_c[o] = sum_m W_ih[o][m]*b_msg[m]
__global__ void prep_weights(const float* __restrict__ W_msg, const float* __restrict__ b_msg,
                             const float* __restrict__ W_ih, const float* __restrict__ W_hh,
                             float* __restrict__ W_cT, float* __restrict__ W_hhT, float* __restrict__ b_c)
{
    int tid = blockIdx.x * blockDim.x + threadIdx.x;
    if (tid >= HDIM * H3) return;
    int o = tid % H3;   // 0..383
    int k = tid / H3;   // 0..127
    float acc = 0.f;
    for (int m = 0; m < HDIM; ++m)
        acc = fmaf(W_ih[o*HDIM + m], W_msg[m*HDIM + k], acc);
    W_cT[k*H3 + o] = acc;
    W_hhT[k*H3 + o] = W_hh[o*HDIM + k];
    if (k == 0) {
        float bb = 0.f;
        for (int m = 0; m < HDIM; ++m) bb = fmaf(W_ih[o*HDIM + m], b_msg[m], bb);
        b_c[o] = bb;
    }
}

__global__ void hist_kernel(const int* __restrict__ eidx, int* __restrict__ deg)
{
    int e = blockIdx.x * blockDim.x + threadIdx.x;
    if (e < N_EDGESC) atomicAdd(&deg[eidx[e]], 1);
}

__global__ void scan_partial(const int* __restrict__ in, int* __restrict__ out,
                             int* __restrict__ bsums, int n)
{
    __shared__ int ts[SCAN_BLOCK];
    int tid = threadIdx.x;
    int base = blockIdx.x * SCAN_CHUNK + tid * 4;
    int v0 = (base+0 < n) ? in[base+0] : 0;
    int v1 = (base+1 < n) ? in[base+1] : 0;
    int v2 = (base+2 < n) ? in[base+2] : 0;
    int v3 = (base+3 < n) ? in[base+3] : 0;
    ts[tid] = v0+v1+v2+v3;
    __syncthreads();
    for (int off = 1; off < SCAN_BLOCK; off <<= 1) {
        int t = (tid >= off) ? ts[tid-off] : 0;
        __syncthreads();
        ts[tid] += t;
        __syncthreads();
    }
    int excl = (tid > 0) ? ts[tid-1] : 0;
    if (tid == SCAN_BLOCK-1) bsums[blockIdx.x] = ts[SCAN_BLOCK-1];
    if (base+0 < n) out[base+0] = excl;
    if (base+1 < n) out[base+1] = excl + v0;
    if (base+2 < n) out[base+2] = excl + v0 + v1;
    if (base+3 < n) out[base+3] = excl + v0 + v1 + v2;
}

__global__ void scan_sums(int* bsums, int nb)
{
    if (threadIdx.x == 0 && blockIdx.x == 0) {
        int run = 0;
        for (int b = 0; b < nb; ++b) { int t = bsums[b]; bsums[b] = run; run += t; }
    }
}

__global__ void scan_add(int* __restrict__ out, const int* __restrict__ bsums, int n)
{
    int i = blockIdx.x * blockDim.x + threadIdx.x;
    if (i < n) out[i] += bsums[i / SCAN_CHUNK];
}

__global__ void copy_cursor(const int* __restrict__ offs, int* __restrict__ cur)
{
    int i = blockIdx.x * blockDim.x + threadIdx.x;
    if (i < N_NODESC) cur[i] = offs[i];
}

__global__ void scatter_edges(const int* __restrict__ eidx, int* __restrict__ cur, int* __restrict__ cols)
{
    int e = blockIdx.x * blockDim.x + threadIdx.x;
    if (e < N_EDGESC) {
        int r = eidx[e];
        int c = eidx[N_EDGESC + e];
        int p = atomicAdd(&cur[r], 1);
        cols[p] = c;
    }
}

// S[i,:] = sum over incoming edges of h[col,:]   (CSR, no atomics)
__global__ void agg_kernel(const float* __restrict__ h, const int* __restrict__ offs,
                           const int* __restrict__ cols, float* __restrict__ S)
{
    int node = blockIdx.x * 2 + (threadIdx.x >> 7);
    int j = threadIdx.x & (HDIM - 1);
    int beg = offs[node], end = offs[node+1];
    float a0 = 0.f, a1 = 0.f;
    int e = beg;
    for (; e + 1 < end; e += 2) {
        int c0 = cols[e], c1 = cols[e+1];
        a0 += h[(size_t)c0*HDIM + j];
        a1 += h[(size_t)c1*HDIM + j];
    }
    if (e < end) a0 += h[(size_t)cols[e]*HDIM + j];
    S[(size_t)node*HDIM + j] = a0 + a1;
}

// Fused GEMMs + GRU gates. 16 nodes per block, 384 threads (one per output column).
// gi = W_c * S_i + deg_i*b_c + b_ih ;  gh = W_hh * h_i + b_hh ;  gates (r,z,n) ; in-place h update.
#define GRU_NT 16
__global__ __launch_bounds__(384) void gru_kernel(
    const float* __restrict__ S, float* __restrict__ h,
    const int* __restrict__ deg,
    const float* __restrict__ W_cT, const float* __restrict__ W_hhT,
    const float* __restrict__ b_c, const float* __restrict__ b_ih, const float* __restrict__ b_hh)
{
    __shared__ float Sl[GRU_NT][HDIM];
    __shared__ float Hl[GRU_NT][HDIM];
    __shared__ float RZ[GRU_NT][2*HDIM];
    __shared__ float NIn[GRU_NT][HDIM];
    __shared__ float NHn[GRU_NT][HDIM];

    int tid = threadIdx.x;
    int i0 = blockIdx.x * GRU_NT;

    for (int idx = tid; idx < GRU_NT*HDIM; idx += 384) {
        int n = idx >> 7, k = idx & (HDIM-1);
        int node = i0 + n;
        Sl[n][k] = S[(size_t)node*HDIM + k];
        Hl[n][k] = h[(size_t)node*HDIM + k];
    }
    __syncthreads();

    int j = tid;  // 0..383 output column
    float acc_i[GRU_NT], acc_h[GRU_NT];
    #pragma unroll
    for (int n = 0; n < GRU_NT; ++n) { acc_i[n] = 0.f; acc_h[n] = 0.f; }

    for (int k = 0; k < HDIM; k += 4) {
        float wc0 = W_cT[(k+0)*H3 + j];
        float wc1 = W_cT[(k+1)*H3 + j];
        float wc2 = W_cT[(k+2)*H3 + j];
        float wc3 = W_cT[(k+3)*H3 + j];
        float wh0 = W_hhT[(k+0)*H3 + j];
        float wh1 = W_hhT[(k+1)*H3 + j];
        float wh2 = W_hhT[(k+2)*H3 + j];
        float wh3 = W_hhT[(k+3)*H3 + j];
        #pragma unroll
        for (int n = 0; n < GRU_NT; ++n) {
            float4 s4 = *reinterpret_cast<const float4*>(&Sl[n][k]);
            float4 h4 = *reinterpret_cast<const float4*>(&Hl[n][k]);
            acc_i[n] = fmaf(s4.x, wc0, acc_i[n]);
            acc_i[n] = fmaf(s4.y, wc1, acc_i[n]);
            acc_i[n] = fmaf(s4.z, wc2, acc_i[n]);
            acc_i[n] = fmaf(s4.w, wc3, acc_i[n]);
            acc_h[n] = fmaf(h4.x, wh0, acc_h[n]);
            acc_h[n] = fmaf(h4.y, wh1, acc_h[n]);
            acc_h[n] = fmaf(h4.z, wh2, acc_h[n]);
            acc_h[n] = fmaf(h4.w, wh3, acc_h[n]);
        }
    }

    float bcj  = b_c[j];
    float bihj = b_ih[j];
    float bhhj = b_hh[j];

    if (j < 2*HDIM) {
        #pragma unroll
        for (int n = 0; n < GRU_NT; ++n) {
            float dg = (float)deg[i0 + n];
            RZ[n][j] = acc_i[n] + dg*bcj + bihj + acc_h[n] + bhhj;
        }
    } else {
        int c = j - 2*HDIM;
        #pragma unroll
        for (int n = 0; n < GRU_NT; ++n) {
            float dg = (float)deg[i0 + n];
            NIn[n][c] = acc_i[n] + dg*bcj + bihj;
            NHn[n][c] = acc_h[n] + bhhj;
        }
    }
    __syncthreads();

    for (int idx = tid; idx < GRU_NT*HDIM; idx += 384) {
        int n = idx >> 7, c = idx & (HDIM-1);
        int node = i0 + n;
        float r  = sigmoidf_(RZ[n][c]);
        float z  = sigmoidf_(RZ[n][HDIM + c]);
        float nn = tanhf(NIn[n][c] + r * NHn[n][c]);
        h[(size_t)node*HDIM + c] = (1.f - z)*nn + z*Hl[n][c];
    }
}

extern "C" void kernel_launch(void* const* d_in, const int* in_sizes, int n_in,
                              void* d_out, int out_size, void* d_ws, size_t ws_size,
                              hipStream_t stream)
{
    const float* x     = (const float*)d_in[0];
    const int*   eidx  = (const int*)d_in[1];   // [2, E] int32 (harness converts integer inputs)
    const float* W_msg = (const float*)d_in[2];
    const float* b_msg = (const float*)d_in[3];
    const float* W_ih  = (const float*)d_in[4];
    const float* W_hh  = (const float*)d_in[5];
    const float* b_ih  = (const float*)d_in[6];
    const float* b_hh  = (const float*)d_in[7];

    float* h = (float*)d_out;   // h lives in d_out (in-place GRU is safe: cross-node coupling only via S)

    char* ws = (char*)d_ws;
    size_t off = 0;
    auto alloc = [&](size_t bytes) -> void* {
        void* p = ws + off;
        off = (off + bytes + 255) & ~(size_t)255;
        return p;
    };
    float* S      = (float*)alloc((size_t)N_NODESC*HDIM*sizeof(float));
    float* W_cT   = (float*)alloc((size_t)HDIM*H3*sizeof(float));
    float* W_hhT  = (float*)alloc((size_t)HDIM*H3*sizeof(float));
    float* b_c    = (float*)alloc(H3*sizeof(float));
    int*   deg    = (int*)alloc((N_NODESC+1)*sizeof(int));
    int*   offs   = (int*)alloc((N_NODESC+1)*sizeof(int));
    int*   cur    = (int*)alloc(N_NODESC*sizeof(int));
    int*   cols   = (int*)alloc(N_EDGESC*sizeof(int));
    int*   bsums  = (int*)alloc(256*sizeof(int));

    hipMemcpyAsync(h, x, (size_t)N_NODESC*HDIM*sizeof(float), hipMemcpyDeviceToDevice, stream);
    hipMemsetAsync(deg, 0, (N_NODESC+1)*sizeof(int), stream);

    prep_weights<<<(HDIM*H3 + 255)/256, 256, 0, stream>>>(W_msg, b_msg, W_ih, W_hh, W_cT, W_hhT, b_c);

    hist_kernel<<<(N_EDGESC + 255)/256, 256, 0, stream>>>(eidx, deg);

    int n_scan = N_NODESC + 1;
    int nb = (n_scan + SCAN_CHUNK - 1) / SCAN_CHUNK;
    scan_partial<<<nb, SCAN_BLOCK, 0, stream>>>(deg, offs, bsums, n_scan);
    scan_sums<<<1, 64, 0, stream>>>(bsums, nb);
    scan_add<<<(n_scan + 255)/256, 256, 0, stream>>>(offs, bsums, n_scan);

    copy_cursor<<<(N_NODESC + 255)/256, 256, 0, stream>>>(offs, cur);
    scatter_edges<<<(N_EDGESC + 255)/256, 256, 0, stream>>>(eidx, cur, cols);

    for (int step = 0; step < NUM_STEPSC; ++step) {
        agg_kernel<<<N_NODESC/2, 256, 0, stream>>>(h, offs, cols, S);
        gru_kernel<<<N_NODESC/GRU_NT, 384, 0, stream>>>(S, h, deg, W_cT, W_hhT, b_c, b_ih, b_hh);
    }
}

// Round 2
// 3056.195 us; speedup vs baseline: 1.0052x; 1.0052x over previous
//
#include <hip/hip_runtime.h>

#define N_NODESC 100000
#define N_EDGESC 600000
#define HDIM 128
#define H3 384
#define NUM_STEPSC 5

#define SCAN_BLOCK 256
#define SCAN_CHUNK 1024

__device__ __forceinline__ float sigmoidf_(float x) { return 1.0f / (1.0f + expf(-x)); }

// W_cT[k][o] = sum_m W_ih[o][m]*W_msg[m][k];  W_hhT[k][o] = W_hh[o][k];  b_c[o] = sum_m W_ih[o][m]*b_msg[m]
__global__ void prep_weights(const float* __restrict__ W_msg, const float* __restrict__ b_msg,
                             const float* __restrict__ W_ih, const float* __restrict__ W_hh,
                             float* __restrict__ W_cT, float* __restrict__ W_hhT, float* __restrict__ b_c)
{
    int tid = blockIdx.x * blockDim.x + threadIdx.x;
    if (tid >= HDIM * H3) return;
    int o = tid % H3;   // 0..383
    int k = tid / H3;   // 0..127
    float acc = 0.f;
    for (int m = 0; m < HDIM; ++m)
        acc = fmaf(W_ih[o*HDIM + m], W_msg[m*HDIM + k], acc);
    W_cT[k*H3 + o] = acc;
    W_hhT[k*H3 + o] = W_hh[o*HDIM + k];
    if (k == 0) {
        float bb = 0.f;
        for (int m = 0; m < HDIM; ++m) bb = fmaf(W_ih[o*HDIM + m], b_msg[m], bb);
        b_c[o] = bb;
    }
}

__global__ void hist_kernel(const int* __restrict__ eidx, int* __restrict__ deg)
{
    int e = blockIdx.x * blockDim.x + threadIdx.x;
    if (e < N_EDGESC) atomicAdd(&deg[eidx[e]], 1);
}

__global__ void scan_partial(const int* __restrict__ in, int* __restrict__ out,
                             int* __restrict__ bsums, int n)
{
    __shared__ int ts[SCAN_BLOCK];
    int tid = threadIdx.x;
    int base = blockIdx.x * SCAN_CHUNK + tid * 4;
    int v0 = (base+0 < n) ? in[base+0] : 0;
    int v1 = (base+1 < n) ? in[base+1] : 0;
    int v2 = (base+2 < n) ? in[base+2] : 0;
    int v3 = (base+3 < n) ? in[base+3] : 0;
    ts[tid] = v0+v1+v2+v3;
    __syncthreads();
    for (int off = 1; off < SCAN_BLOCK; off <<= 1) {
        int t = (tid >= off) ? ts[tid-off] : 0;
        __syncthreads();
        ts[tid] += t;
        __syncthreads();
    }
    int excl = (tid > 0) ? ts[tid-1] : 0;
    if (tid == SCAN_BLOCK-1) bsums[blockIdx.x] = ts[SCAN_BLOCK-1];
    if (base+0 < n) out[base+0] = excl;
    if (base+1 < n) out[base+1] = excl + v0;
    if (base+2 < n) out[base+2] = excl + v0 + v1;
    if (base+3 < n) out[base+3] = excl + v0 + v1 + v2;
}

__global__ void scan_sums(int* bsums, int nb)
{
    if (threadIdx.x == 0 && blockIdx.x == 0) {
        int run = 0;
        for (int b = 0; b < nb; ++b) { int t = bsums[b]; bsums[b] = run; run += t; }
    }
}

__global__ void scan_add(int* __restrict__ out, const int* __restrict__ bsums, int n)
{
    int i = blockIdx.x * blockDim.x + threadIdx.x;
    if (i < n) out[i] += bsums[i / SCAN_CHUNK];
}

__global__ void copy_cursor(const int* __restrict__ offs, int* __restrict__ cur)
{
    int i = blockIdx.x * blockDim.x + threadIdx.x;
    if (i < N_NODESC) cur[i] = offs[i];
}

__global__ void scatter_edges(const int* __restrict__ eidx, int* __restrict__ cur, int* __restrict__ cols)
{
    int e = blockIdx.x * blockDim.x + threadIdx.x;
    if (e < N_EDGESC) {
        int r = eidx[e];
        int c = eidx[N_EDGESC + e];
        int p = atomicAdd(&cur[r], 1);
        cols[p] = c;
    }
}

// S[i,:] = sum over incoming edges of h[col,:]   (CSR, no atomics)
__global__ void agg_kernel(const float* __restrict__ h, const int* __restrict__ offs,
                           const int* __restrict__ cols, float* __restrict__ S)
{
    int node = blockIdx.x * 2 + (threadIdx.x >> 7);
    int j = threadIdx.x & (HDIM - 1);
    int beg = offs[node], end = offs[node+1];
    float a0 = 0.f, a1 = 0.f;
    int e = beg;
    for (; e + 1 < end; e += 2) {
        int c0 = cols[e], c1 = cols[e+1];
        a0 += h[(size_t)c0*HDIM + j];
        a1 += h[(size_t)c1*HDIM + j];
    }
    if (e < end) a0 += h[(size_t)cols[e]*HDIM + j];
    S[(size_t)node*HDIM + j] = a0 + a1;
}

// Fused GEMMs + GRU gates. 16 nodes per block, 384 threads (one per output column).
// gi = W_c * S_i + deg_i*b_c + b_ih ;  gh = W_hh * h_i + b_hh ;  gates (r,z,n) ; in-place h update.
#define GRU_NT 16
__global__ __launch_bounds__(384) void gru_kernel(
    const float* __restrict__ S, float* __restrict__ h,
    const int* __restrict__ deg,
    const float* __restrict__ W_cT, const float* __restrict__ W_hhT,
    const float* __restrict__ b_c, const float* __restrict__ b_ih, const float* __restrict__ b_hh)
{
    __shared__ float Sl[GRU_NT][HDIM];
    __shared__ float Hl[GRU_NT][HDIM];
    __shared__ float RZ[GRU_NT][2*HDIM];
    __shared__ float NIn[GRU_NT][HDIM];
    __shared__ float NHn[GRU_NT][HDIM];

    int tid = threadIdx.x;
    int i0 = blockIdx.x * GRU_NT;

    for (int idx = tid; idx < GRU_NT*HDIM; idx += 384) {
        int n = idx >> 7, k = idx & (HDIM-1);
        int node = i0 + n;
        Sl[n][k] = S[(size_t)node*HDIM + k];
        Hl[n][k] = h[(size_t)node*HDIM + k];
    }
    __syncthreads();

    int j = tid;  // 0..383 output column
    float acc_i[GRU_NT], acc_h[GRU_NT];
    #pragma unroll
    for (int n = 0; n < GRU_NT; ++n) { acc_i[n] = 0.f; acc_h[n] = 0.f; }

    for (int k = 0; k < HDIM; k += 4) {
        float wc0 = W_cT[(k+0)*H3 + j];
        float wc1 = W_cT[(k+1)*H3 + j];
        float wc2 = W_cT[(k+2)*H3 + j];
        float wc3 = W_cT[(k+3)*H3 + j];
        float wh0 = W_hhT[(k+0)*H3 + j];
        float wh1 = W_hhT[(k+1)*H3 + j];
        float wh2 = W_hhT[(k+2)*H3 + j];
        float wh3 = W_hhT[(k+3)*H3 + j];
        #pragma unroll
        for (int n = 0; n < GRU_NT; ++n) {
            float4 s4 = *reinterpret_cast<const float4*>(&Sl[n][k]);
            float4 h4 = *reinterpret_cast<const float4*>(&Hl[n][k]);
            acc_i[n] = fmaf(s4.x, wc0, acc_i[n]);
            acc_i[n] = fmaf(s4.y, wc1, acc_i[n]);
            acc_i[n] = fmaf(s4.z, wc2, acc_i[n]);
            acc_i[n] = fmaf(s4.w, wc3, acc_i[n]);
            acc_h[n] = fmaf(h4.x, wh0, acc_h[n]);
            acc_h[n] = fmaf(h4.y, wh1, acc_h[n]);
            acc_h[n] = fmaf(h4.z, wh2, acc_h[n]);
            acc_h[n] = fmaf(h4.w, wh3, acc_h[n]);
        }
    }

    float bcj  = b_c[j];
    float bihj = b_ih[j];
    float bhhj = b_hh[j];

    if (j < 2*HDIM) {
        #pragma unroll
        for (int n = 0; n < GRU_NT; ++n) {
            float dg = (float)deg[i0 + n];
            RZ[n][j] = acc_i[n] + dg*bcj + bihj + acc_h[n] + bhhj;
        }
    } else {
        int c = j - 2*HDIM;
        #pragma unroll
        for (int n = 0; n < GRU_NT; ++n) {
            float dg = (float)deg[i0 + n];
            NIn[n][c] = acc_i[n] + dg*bcj + bihj;
            NHn[n][c] = acc_h[n] + bhhj;
        }
    }
    __syncthreads();

    for (int idx = tid; idx < GRU_NT*HDIM; idx += 384) {
        int n = idx >> 7, c = idx & (HDIM-1);
        int node = i0 + n;
        float r  = sigmoidf_(RZ[n][c]);
        float z  = sigmoidf_(RZ[n][HDIM + c]);
        float nn = tanhf(NIn[n][c] + r * NHn[n][c]);
        h[(size_t)node*HDIM + c] = (1.f - z)*nn + z*Hl[n][c];
    }
}

extern "C" void kernel_launch(void* const* d_in, const int* in_sizes, int n_in,
                              void* d_out, int out_size, void* d_ws, size_t ws_size,
                              hipStream_t stream)
{
    const float* x     = (const float*)d_in[0];
    const int*   eidx  = (const int*)d_in[1];   // [2, E] int32 (harness converts integer inputs)
    const float* W_msg = (const float*)d_in[2];
    const float* b_msg = (const float*)d_in[3];
    const float* W_ih  = (const float*)d_in[4];
    const float* W_hh  = (const float*)d_in[5];
    const float* b_ih  = (const float*)d_in[6];
    const float* b_hh  = (const float*)d_in[7];

    float* h = (float*)d_out;   // h lives in d_out (in-place GRU is safe: cross-node coupling only via S)

    char* ws = (char*)d_ws;
    size_t off = 0;
    auto alloc = [&](size_t bytes) -> void* {
        void* p = ws + off;
        off = (off + bytes + 255) & ~(size_t)255;
        return p;
    };
    float* S      = (float*)alloc((size_t)N_NODESC*HDIM*sizeof(float));
    float* W_cT   = (float*)alloc((size_t)HDIM*H3*sizeof(float));
    float* W_hhT  = (float*)alloc((size_t)HDIM*H3*sizeof(float));
    float* b_c    = (float*)alloc(H3*sizeof(float));
    int*   deg    = (int*)alloc((N_NODESC+1)*sizeof(int));
    int*   offs   = (int*)alloc((N_NODESC+1)*sizeof(int));
    int*   cur    = (int*)alloc(N_NODESC*sizeof(int));
    int*   cols   = (int*)alloc(N_EDGESC*sizeof(int));
    int*   bsums  = (int*)alloc(256*sizeof(int));

    hipMemcpyAsync(h, x, (size_t)N_NODESC*HDIM*sizeof(float), hipMemcpyDeviceToDevice, stream);
    hipMemsetAsync(deg, 0, (N_NODESC+1)*sizeof(int), stream);

    prep_weights<<<(HDIM*H3 + 255)/256, 256, 0, stream>>>(W_msg, b_msg, W_ih, W_hh, W_cT, W_hhT, b_c);

    hist_kernel<<<(N_EDGESC + 255)/256, 256, 0, stream>>>(eidx, deg);

    int n_scan = N_NODESC + 1;
    int nb = (n_scan + SCAN_CHUNK - 1) / SCAN_CHUNK;
    scan_partial<<<nb, SCAN_BLOCK, 0, stream>>>(deg, offs, bsums, n_scan);
    scan_sums<<<1, 64, 0, stream>>>(bsums, nb);
    scan_add<<<(n_scan + 255)/256, 256, 0, stream>>>(offs, bsums, n_scan);

    copy_cursor<<<(N_NODESC + 255)/256, 256, 0, stream>>>(offs, cur);
    scatter_edges<<<(N_EDGESC + 255)/256, 256, 0, stream>>>(eidx, cur, cols);

    for (int step = 0; step < NUM_STEPSC; ++step) {
        agg_kernel<<<N_NODESC/2, 256, 0, stream>>>(h, offs, cols, S);
        gru_kernel<<<N_NODESC/GRU_NT, 384, 0, stream>>>(S, h, deg, W_cT, W_hhT, b_c, b_ih, b_hh);
    }
}